// Round 6
// baseline (367.828 us; speedup 1.0000x reference)
//
#include <hip/hip_runtime.h>

#define N_NODES 100000
#define N_EDGES 1250000
#define D 64
#define ED 32
#define SCAN_BS 512
#define SCAN_NB 196   // ceil(100000/512)

typedef unsigned int uint;
typedef unsigned short ushort;

// bf16 round-to-nearest-even helpers
__device__ __forceinline__ uint bfr(float f) {
    uint u = __float_as_uint(f);
    return (u + 0x7FFFu + ((u >> 16) & 1u)) >> 16;
}
__device__ __forceinline__ uint pk(float a, float b) { return bfr(a) | (bfr(b) << 16); }
__device__ __forceinline__ float bfu(ushort s) { return __uint_as_float(((uint)s) << 16); }

// ---------------- CSR build ----------------

__global__ void __launch_bounds__(256) hist_k(const int* __restrict__ col,
                                              int* __restrict__ cnt) {
    int i = blockIdx.x * blockDim.x + threadIdx.x;
    int stride = gridDim.x * blockDim.x;
    const int4* c4 = (const int4*)col;
    for (int j = i; j < N_EDGES / 4; j += stride) {
        int4 c = c4[j];
        atomicAdd(&cnt[c.x], 1); atomicAdd(&cnt[c.y], 1);
        atomicAdd(&cnt[c.z], 1); atomicAdd(&cnt[c.w], 1);
    }
}

__global__ void __launch_bounds__(SCAN_BS) scan_local_k(const int* __restrict__ cnt,
                                                        int* __restrict__ base,
                                                        int* __restrict__ bsum) {
    __shared__ int s[SCAN_BS];
    const int t = threadIdx.x;
    const int i = blockIdx.x * SCAN_BS + t;
    const int v = (i < N_NODES) ? cnt[i] : 0;
    s[t] = v;
    __syncthreads();
    for (int off = 1; off < SCAN_BS; off <<= 1) {
        int tv = (t >= off) ? s[t - off] : 0;
        __syncthreads();
        s[t] += tv;
        __syncthreads();
    }
    if (i < N_NODES) base[i] = s[t] - v;
    if (t == SCAN_BS - 1) bsum[blockIdx.x] = s[t];
}

__global__ void __launch_bounds__(256) scan_bsum_k(const int* __restrict__ bsum,
                                                   int* __restrict__ boff) {
    __shared__ int s[256];
    const int t = threadIdx.x;
    const int v = (t < SCAN_NB) ? bsum[t] : 0;
    s[t] = v;
    __syncthreads();
    for (int off = 1; off < 256; off <<= 1) {
        int tv = (t >= off) ? s[t - off] : 0;
        __syncthreads();
        s[t] += tv;
        __syncthreads();
    }
    if (t < SCAN_NB) boff[t] = s[t] - v;
}

__global__ void __launch_bounds__(SCAN_BS) scan_add_k(int* __restrict__ base,
                                                      const int* __restrict__ boff,
                                                      int* __restrict__ cursor) {
    const int i = blockIdx.x * SCAN_BS + threadIdx.x;
    if (i < N_NODES) {
        const int b = base[i] + boff[blockIdx.x];
        base[i] = b;
        cursor[i] = b;
    }
    if (i == 0) base[N_NODES] = N_EDGES;
}

// ---------------- payload permute: eap[pos] = bf16(ea[e]), rowp[pos] = row[e] ----------------

__global__ void __launch_bounds__(256) scatter_perm_k(const int* __restrict__ row,
                                                      const int* __restrict__ col,
                                                      int* __restrict__ cursor,
                                                      const float* __restrict__ ea,
                                                      int* __restrict__ rowp,
                                                      ushort* __restrict__ eap) {
    int i = blockIdx.x * blockDim.x + threadIdx.x;
    int stride = gridDim.x * blockDim.x;
    for (int e = i; e < N_EDGES; e += stride) {
        const int c = col[e];
        const int r = row[e];
        const int pos = atomicAdd(&cursor[c], 1);
        rowp[pos] = r;
        const float4* src = (const float4*)(ea + (size_t)e * ED);
        uint4 o[4];
#pragma unroll
        for (int q = 0; q < 4; ++q) {
            const float4 va = src[2 * q];
            const float4 vb = src[2 * q + 1];
            o[q].x = pk(va.x, va.y); o[q].y = pk(va.z, va.w);
            o[q].z = pk(vb.x, vb.y); o[q].w = pk(vb.z, vb.w);
        }
        uint4* dst = (uint4*)(eap + (size_t)pos * ED);
        dst[0] = o[0]; dst[1] = o[1]; dst[2] = o[2]; dst[3] = o[3];
    }
}

// ---------------- precompute: xl16 = bf16(x @ lw^T)  [N][64] ----------------

__global__ void __launch_bounds__(256) xl16_k(const float* __restrict__ x,
                                              const float* __restrict__ lw,
                                              ushort* __restrict__ xl) {
    const int lane = threadIdx.x & 63;
    const int wid  = blockIdx.x * (blockDim.x >> 6) + (threadIdx.x >> 6);
    const int nw   = gridDim.x * (blockDim.x >> 6);

    float w[D];
    const float4* lw4 = (const float4*)(lw + (size_t)lane * D);
#pragma unroll
    for (int q = 0; q < D / 4; ++q) {
        const float4 v = lw4[q];
        w[4*q+0] = v.x; w[4*q+1] = v.y; w[4*q+2] = v.z; w[4*q+3] = v.w;
    }

    for (int n = wid; n < N_NODES; n += nw) {
        const float4* xx = (const float4*)(x + (size_t)n * D);
        float d0 = 0.f, d1 = 0.f;
#pragma unroll
        for (int q = 0; q < D / 8; ++q) {
            const float4 v0 = xx[q];
            const float4 v1 = xx[q + 8];
            d0 = fmaf(v0.x, w[4*q+0], d0);  d0 = fmaf(v0.y, w[4*q+1], d0);
            d0 = fmaf(v0.z, w[4*q+2], d0);  d0 = fmaf(v0.w, w[4*q+3], d0);
            d1 = fmaf(v1.x, w[4*q+32], d1); d1 = fmaf(v1.y, w[4*q+33], d1);
            d1 = fmaf(v1.z, w[4*q+34], d1); d1 = fmaf(v1.w, w[4*q+35], d1);
        }
        xl[(size_t)n * D + lane] = (ushort)bfr(d0 + d1);
    }
}

// ---------------- weight folding: Cmat = lw@ew [64][32], lwb = lw@eb [64] ----------------

__global__ void __launch_bounds__(256) combine_k(const float* __restrict__ lw,
                                                 const float* __restrict__ ew,
                                                 const float* __restrict__ eb,
                                                 float* __restrict__ Cmat,
                                                 float* __restrict__ lwb) {
    const int idx = blockIdx.x * blockDim.x + threadIdx.x;   // 8*256 = 2048
    if (idx < D * ED) {
        const int d = idx >> 5, j = idx & 31;
        float s = 0.f;
#pragma unroll
        for (int k = 0; k < D; ++k) s = fmaf(lw[d * D + k], ew[k * ED + j], s);
        Cmat[idx] = s;
    }
    if (idx < D) {
        float s = 0.f;
#pragma unroll
        for (int k = 0; k < D; ++k) s = fmaf(lw[idx * D + k], eb[k], s);
        lwb[idx] = s;
    }
}

// ---------------- fused aggregation + output ----------------
// out[n][d] = inv * ( segsum(xl[row]) + Cmat · segsum(ea) )[d] + [deg>0]*lwb[d] + lb[d]
// 8 unconditional loads per round -> 8+ outstanding VMEM per wave.

__global__ void __launch_bounds__(256) agg_final_k(const ushort* __restrict__ xl,
                                                   const int* __restrict__ base,
                                                   const int* __restrict__ rowp,
                                                   const ushort* __restrict__ eap,
                                                   const float* __restrict__ Cmat,
                                                   const float* __restrict__ lwb,
                                                   const float* __restrict__ lb,
                                                   float* __restrict__ out) {
    const int lane = threadIdx.x & 63;
    const int wid  = blockIdx.x * (blockDim.x >> 6) + (threadIdx.x >> 6);
    const int nw   = gridDim.x * (blockDim.x >> 6);

    const float lwbl = lwb[lane];
    const float lbl  = lb[lane];
    const float4* cm4 = (const float4*)(Cmat + (size_t)lane * ED);  // L1-hot after 1st node

    const int npw = (N_NODES + nw - 1) / nw;      // contiguous node range per wave
    const int n0 = wid * npw;
    const int n1 = min(n0 + npw, N_NODES);

    for (int n = n0; n < n1; ++n) {
        const int j0 = base[n], j1 = base[n + 1];
        float ax[8] = {0,0,0,0,0,0,0,0};
        float ae[8] = {0,0,0,0,0,0,0,0};

        for (int jb = j0; jb < j1; jb += 64) {
            const int cnt = min(64, j1 - jb);               // wave-uniform
            const int r = rowp[jb + min(lane, cnt - 1)];    // coalesced

            // x side: rounds of 8 unconditional gathers (128B rows from xl16)
            for (int k = 0; k < cnt; k += 8) {
                float vx[8];
#pragma unroll
                for (int i = 0; i < 8; ++i) {
                    const int ri = __shfl(r, min(k + i, cnt - 1));
                    vx[i] = bfu(xl[(size_t)ri * D + lane]);
                }
#pragma unroll
                for (int i = 0; i < 8; ++i) ax[i] += (k + i < cnt) ? vx[i] : 0.f;
            }

            // ea side: sequential bf16 stream, 2 edges/128B load, rounds of 8
            const int npair = cnt >> 1;
            const ushort* ep = eap + (size_t)jb * ED + lane;
            for (int t = 0; t < npair; t += 8) {
                float ve[8];
#pragma unroll
                for (int i = 0; i < 8; ++i)
                    ve[i] = bfu(ep[(size_t)min(t + i, npair - 1) * 64]);
#pragma unroll
                for (int i = 0; i < 8; ++i) ae[i] += (t + i < npair) ? ve[i] : 0.f;
            }
            if ((cnt & 1) && lane < 32)
                ae[0] += bfu(eap[(size_t)(jb + cnt - 1) * ED + lane]);
        }

        float axs = ((ax[0]+ax[1])+(ax[2]+ax[3])) + ((ax[4]+ax[5])+(ax[6]+ax[7]));
        float aes = ((ae[0]+ae[1])+(ae[2]+ae[3])) + ((ae[4]+ae[5])+(ae[6]+ae[7]));
        aes += __shfl_xor(aes, 32);          // every lane: full segsum(ea)[n][lane%32]

        float zd = axs;
#pragma unroll
        for (int q = 0; q < ED / 4; ++q) {
            const float4 wv = cm4[q];
            zd = fmaf(__shfl(aes, 4*q+0), wv.x, zd);
            zd = fmaf(__shfl(aes, 4*q+1), wv.y, zd);
            zd = fmaf(__shfl(aes, 4*q+2), wv.z, zd);
            zd = fmaf(__shfl(aes, 4*q+3), wv.w, zd);
        }
        const int dg = j1 - j0;
        const float inv = 1.f / fmaxf((float)dg, 1.f);
        out[(size_t)n * D + lane] = fmaf(inv, zd, (dg > 0 ? lwbl : 0.f) + lbl);
    }
}

// ---------------- tier A2 (proven R5 path, ws >= ~86MB) ----------------

__global__ void __launch_bounds__(256) agg_k(const float* __restrict__ x,
                                             const int* __restrict__ base,
                                             const int* __restrict__ rowp,
                                             const ushort* __restrict__ eap,
                                             const float* __restrict__ ew,
                                             const float* __restrict__ eb,
                                             float* __restrict__ z) {
    const int lane = threadIdx.x & 63;
    const int wid  = blockIdx.x * (blockDim.x >> 6) + (threadIdx.x >> 6);
    const int nw   = gridDim.x * (blockDim.x >> 6);

    float w[ED];
    const float4* ew4 = (const float4*)(ew + (size_t)lane * ED);
#pragma unroll
    for (int q = 0; q < ED / 4; ++q) {
        const float4 v = ew4[q];
        w[4*q+0] = v.x; w[4*q+1] = v.y; w[4*q+2] = v.z; w[4*q+3] = v.w;
    }
    const float ebl = eb[lane];

    const int npw = (N_NODES + nw - 1) / nw;
    const int n0 = wid * npw;
    const int n1 = min(n0 + npw, N_NODES);

    for (int n = n0; n < n1; ++n) {
        const int j0 = base[n], j1 = base[n + 1];
        float ax0 = 0.f, ax1 = 0.f, ax2 = 0.f, ax3 = 0.f;
        float a0 = 0.f, a1 = 0.f, a2 = 0.f, a3 = 0.f;

        for (int jb = j0; jb < j1; jb += 64) {
            const int cnt = min(64, j1 - jb);
            int r = 0;
            if (lane < cnt) r = rowp[jb + lane];
            int k = 0;
            for (; k + 3 < cnt; k += 4) {
                const int r0 = __shfl(r, k),     r1 = __shfl(r, k + 1);
                const int r2 = __shfl(r, k + 2), r3 = __shfl(r, k + 3);
                ax0 += x[(size_t)r0 * D + lane];
                ax1 += x[(size_t)r1 * D + lane];
                ax2 += x[(size_t)r2 * D + lane];
                ax3 += x[(size_t)r3 * D + lane];
            }
            for (; k < cnt; ++k) ax0 += x[(size_t)__shfl(r, k) * D + lane];

            const ushort* ep = eap + (size_t)jb * ED + lane;
            const int npair = cnt >> 1;
            int t = 0;
            for (; t + 3 < npair; t += 4) {
                a0 += bfu(ep[(t + 0) * 64]);
                a1 += bfu(ep[(t + 1) * 64]);
                a2 += bfu(ep[(t + 2) * 64]);
                a3 += bfu(ep[(t + 3) * 64]);
            }
            for (; t < npair; ++t) a0 += bfu(ep[t * 64]);
            if (cnt & 1) {
                if (lane < 32) a0 += bfu(eap[(size_t)(jb + cnt - 1) * ED + lane]);
            }
        }

        float a32 = (a0 + a1) + (a2 + a3);
        a32 += __shfl_xor(a32, 32);

        float zd = (ax0 + ax1) + (ax2 + ax3);
#pragma unroll
        for (int j = 0; j < ED; ++j)
            zd = fmaf(__shfl(a32, j), w[j], zd);
        zd = fmaf((float)(j1 - j0), ebl, zd);
        z[(size_t)n * D + lane] = zd;
    }
}

__global__ void __launch_bounds__(256) out_k(float* __restrict__ z,
                                             const int* __restrict__ base,
                                             const float* __restrict__ lw,
                                             const float* __restrict__ lb) {
    const int lane = threadIdx.x & 63;
    const int wid  = blockIdx.x * (blockDim.x >> 6) + (threadIdx.x >> 6);
    const int nw   = gridDim.x * (blockDim.x >> 6);

    float w[D];
    const float4* lw4 = (const float4*)(lw + (size_t)lane * D);
#pragma unroll
    for (int q = 0; q < D / 4; ++q) {
        const float4 v = lw4[q];
        w[4*q+0] = v.x; w[4*q+1] = v.y; w[4*q+2] = v.z; w[4*q+3] = v.w;
    }
    const float bias = lb[lane];

    for (int n = wid; n < N_NODES; n += nw) {
        const int dg = base[n + 1] - base[n];
        const float inv = 1.f / fmaxf((float)dg, 1.f);
        const float4* zz = (const float4*)(z + (size_t)n * D);
        float d0 = 0.f, d1 = 0.f;
#pragma unroll
        for (int q = 0; q < D / 8; ++q) {
            const float4 v0 = zz[q];
            const float4 v1 = zz[q + 8];
            d0 = fmaf(v0.x, w[4*q+0], d0);  d0 = fmaf(v0.y, w[4*q+1], d0);
            d0 = fmaf(v0.z, w[4*q+2], d0);  d0 = fmaf(v0.w, w[4*q+3], d0);
            d1 = fmaf(v1.x, w[4*q+32], d1); d1 = fmaf(v1.y, w[4*q+33], d1);
            d1 = fmaf(v1.z, w[4*q+34], d1); d1 = fmaf(v1.w, w[4*q+35], d1);
        }
        z[(size_t)n * D + lane] = fmaf(inv, d0 + d1, bias);
    }
}

// ---------------- tier C (tiny ws): atomic version ----------------

__global__ void __launch_bounds__(256) edge_scatter_fb(
    const float* __restrict__ x, const int* __restrict__ ei,
    const float* __restrict__ ea, const float* __restrict__ ew,
    const float* __restrict__ eb, float* __restrict__ agg, float* __restrict__ deg) {
    const int lane = threadIdx.x & 63;
    const int wid  = blockIdx.x * (blockDim.x >> 6) + (threadIdx.x >> 6);
    const int nw   = gridDim.x * (blockDim.x >> 6);
    float w[ED];
#pragma unroll
    for (int k = 0; k < ED; ++k) w[k] = ew[lane * ED + k];
    const float b = eb[lane];
    for (int e = wid; e < N_EDGES; e += nw) {
        const int r = ei[e];
        const int c = ei[N_EDGES + e];
        const float4* ea4 = (const float4*)(ea + (size_t)e * ED);
        float acc = b;
#pragma unroll
        for (int q = 0; q < ED / 4; ++q) {
            float4 v = ea4[q];
            acc = fmaf(v.x, w[4*q+0], acc); acc = fmaf(v.y, w[4*q+1], acc);
            acc = fmaf(v.z, w[4*q+2], acc); acc = fmaf(v.w, w[4*q+3], acc);
        }
        acc += x[(size_t)r * D + lane];
        atomicAdd(&agg[(size_t)c * D + lane], acc);
        if (lane == 0) atomicAdd(&deg[c], 1.0f);
    }
}

__global__ void __launch_bounds__(256) node_linear_fb(
    float* __restrict__ agg, const float* __restrict__ deg,
    const float* __restrict__ lw, const float* __restrict__ lb) {
    const int lane = threadIdx.x & 63;
    const int wid  = blockIdx.x * (blockDim.x >> 6) + (threadIdx.x >> 6);
    const int nw   = gridDim.x * (blockDim.x >> 6);
    float w[D];
#pragma unroll
    for (int k = 0; k < D; ++k) w[k] = lw[lane * D + k];
    const float b = lb[lane];
    for (int n = wid; n < N_NODES; n += nw) {
        const float inv = 1.0f / fmaxf(deg[n], 1.0f);
        const float4* a4 = (const float4*)(agg + (size_t)n * D);
        float dot = 0.0f;
#pragma unroll
        for (int q = 0; q < D / 4; ++q) {
            float4 v = a4[q];
            dot = fmaf(v.x, w[4*q+0], dot); dot = fmaf(v.y, w[4*q+1], dot);
            dot = fmaf(v.z, w[4*q+2], dot); dot = fmaf(v.w, w[4*q+3], dot);
        }
        agg[(size_t)n * D + lane] = fmaf(inv, dot, b);
    }
}

// ---------------- launch ----------------

extern "C" void kernel_launch(void* const* d_in, const int* in_sizes, int n_in,
                              void* d_out, int out_size, void* d_ws, size_t ws_size,
                              hipStream_t stream) {
    const float* x  = (const float*)d_in[0];
    const int*   ei = (const int*)d_in[1];     // [2][E]: rows then cols
    const float* ea = (const float*)d_in[2];
    const float* lw = (const float*)d_in[3];
    const float* lb = (const float*)d_in[4];
    const float* ew = (const float*)d_in[5];
    const float* eb = (const float*)d_in[6];
    const int* row = ei;
    const int* col = ei + N_EDGES;

    char* ws = (char*)d_ws;
    float* zout = (float*)d_out;

    // ---- tier A: permuted bf16 payload + xl16 + fused epilogue (~98.6 MB) ----
    const size_t A_EAP  = 0;                       // 80,000,000
    const size_t A_ROWP = 80000000;                //  5,000,000
    const size_t A_XL   = 85000000;                // 12,800,000
    const size_t A_CNT  = 97800000;                //    400,000
    const size_t A_BASE = 98200000;                //    400,004 (+pad)
    const size_t A_BSUM = 98600064;
    const size_t A_BOFF = 98600896;
    const size_t A_CMAT = 98601728;                //      8,192
    const size_t A_LWB  = 98609920;                //        256
    const size_t REQ_A  = 98610176;

    // ---- tier A2: R5 exact (~85.8 MB) ----
    const size_t B_EAP  = 0;
    const size_t B_ROWP = (size_t)N_EDGES * ED * 2 + 64;
    const size_t B_CNT  = B_ROWP + (size_t)N_EDGES * 4;
    const size_t B_BASE = B_CNT + 400000;
    const size_t B_BSUM = B_BASE + 400016;
    const size_t B_BOFF = B_BSUM + 784;
    const size_t REQ_B  = B_BOFF + 784;

    if (ws_size >= REQ_A) {
        ushort* eap  = (ushort*)(ws + A_EAP);
        int*    rowp = (int*)(ws + A_ROWP);
        ushort* xl   = (ushort*)(ws + A_XL);
        int*    cnt  = (int*)(ws + A_CNT);
        int*    base = (int*)(ws + A_BASE);
        int*    bsum = (int*)(ws + A_BSUM);
        int*    boff = (int*)(ws + A_BOFF);
        float*  Cmat = (float*)(ws + A_CMAT);
        float*  lwbv = (float*)(ws + A_LWB);

        hipMemsetAsync(cnt, 0, (size_t)N_NODES * sizeof(int), stream);
        hist_k        <<<1024, 256, 0, stream>>>(col, cnt);
        scan_local_k  <<<SCAN_NB, SCAN_BS, 0, stream>>>(cnt, base, bsum);
        scan_bsum_k   <<<1, 256, 0, stream>>>(bsum, boff);
        scan_add_k    <<<SCAN_NB, SCAN_BS, 0, stream>>>(base, boff, cnt /*cursor*/);
        xl16_k        <<<1024, 256, 0, stream>>>(x, lw, xl);
        combine_k     <<<8, 256, 0, stream>>>(lw, ew, eb, Cmat, lwbv);
        scatter_perm_k<<<4096, 256, 0, stream>>>(row, col, cnt /*cursor*/, ea, rowp, eap);
        agg_final_k   <<<2048, 256, 0, stream>>>(xl, base, rowp, eap, Cmat, lwbv, lb, zout);
    } else if (ws_size >= REQ_B) {
        ushort* eap  = (ushort*)(ws + B_EAP);
        int*    rowp = (int*)(ws + B_ROWP);
        int*    cnt  = (int*)(ws + B_CNT);
        int*    base = (int*)(ws + B_BASE);
        int*    bsum = (int*)(ws + B_BSUM);
        int*    boff = (int*)(ws + B_BOFF);

        hipMemsetAsync(cnt, 0, (size_t)N_NODES * sizeof(int), stream);
        hist_k        <<<1024, 256, 0, stream>>>(col, cnt);
        scan_local_k  <<<SCAN_NB, SCAN_BS, 0, stream>>>(cnt, base, bsum);
        scan_bsum_k   <<<1, 256, 0, stream>>>(bsum, boff);
        scan_add_k    <<<SCAN_NB, SCAN_BS, 0, stream>>>(base, boff, cnt /*cursor*/);
        scatter_perm_k<<<2048, 256, 0, stream>>>(row, col, cnt /*cursor*/, ea, rowp, eap);
        agg_k         <<<2048, 256, 0, stream>>>(x, base, rowp, eap, ew, eb, zout);
        out_k         <<<1024, 256, 0, stream>>>(zout, base, lw, lb);
    } else {
        float* deg = (float*)d_ws;
        hipMemsetAsync(zout, 0, (size_t)N_NODES * D * sizeof(float), stream);
        hipMemsetAsync(deg, 0, (size_t)N_NODES * sizeof(float), stream);
        edge_scatter_fb<<<2048, 256, 0, stream>>>(x, ei, ea, ew, eb, zout, deg);
        node_linear_fb <<<1024, 256, 0, stream>>>(zout, deg, lw, lb);
    }
}

// Round 7
// 340.336 us; speedup vs baseline: 1.0808x; 1.0808x over previous
//
#include <hip/hip_runtime.h>

#define N_NODES 100000
#define N_EDGES 1250000
#define D 64
#define ED 32
#define SCAN_BS 512
#define SCAN_NB 196   // ceil(100000/512)

typedef unsigned int uint;
typedef unsigned short ushort;

// bf16 round-to-nearest-even helpers
__device__ __forceinline__ uint bfr(float f) {
    uint u = __float_as_uint(f);
    return (u + 0x7FFFu + ((u >> 16) & 1u)) >> 16;
}
__device__ __forceinline__ float bfu(ushort s) { return __uint_as_float(((uint)s) << 16); }

// ---------------- fused prep: hist (blocks 0..1023) | xl16 (1024..2047) | combine (2048) ----

__global__ void __launch_bounds__(256) prep_k(const int* __restrict__ col,
                                              int* __restrict__ cnt,
                                              const float* __restrict__ x,
                                              const float* __restrict__ lw,
                                              ushort* __restrict__ xl,
                                              const float* __restrict__ ew,
                                              const float* __restrict__ eb,
                                              float* __restrict__ Cmat,
                                              float* __restrict__ lwb) {
    const int bid = blockIdx.x;
    if (bid < 1024) {
        // ---- histogram of col ----
        int i = bid * blockDim.x + threadIdx.x;
        const int stride = 1024 * blockDim.x;
        const int4* c4 = (const int4*)col;
        for (int j = i; j < N_EDGES / 4; j += stride) {
            int4 c = c4[j];
            atomicAdd(&cnt[c.x], 1); atomicAdd(&cnt[c.y], 1);
            atomicAdd(&cnt[c.z], 1); atomicAdd(&cnt[c.w], 1);
        }
    } else if (bid < 2048) {
        // ---- xl16 = bf16(x @ lw^T) ----
        const int lane = threadIdx.x & 63;
        const int wid  = (bid - 1024) * 4 + (threadIdx.x >> 6);
        const int nw   = 1024 * 4;

        float w[D];
        const float4* lw4 = (const float4*)(lw + (size_t)lane * D);
#pragma unroll
        for (int q = 0; q < D / 4; ++q) {
            const float4 v = lw4[q];
            w[4*q+0] = v.x; w[4*q+1] = v.y; w[4*q+2] = v.z; w[4*q+3] = v.w;
        }
        for (int n = wid; n < N_NODES; n += nw) {
            const float4* xx = (const float4*)(x + (size_t)n * D);
            float d0 = 0.f, d1 = 0.f;
#pragma unroll
            for (int q = 0; q < D / 8; ++q) {
                const float4 v0 = xx[q];
                const float4 v1 = xx[q + 8];
                d0 = fmaf(v0.x, w[4*q+0], d0);  d0 = fmaf(v0.y, w[4*q+1], d0);
                d0 = fmaf(v0.z, w[4*q+2], d0);  d0 = fmaf(v0.w, w[4*q+3], d0);
                d1 = fmaf(v1.x, w[4*q+32], d1); d1 = fmaf(v1.y, w[4*q+33], d1);
                d1 = fmaf(v1.z, w[4*q+34], d1); d1 = fmaf(v1.w, w[4*q+35], d1);
            }
            xl[(size_t)n * D + lane] = (ushort)bfr(d0 + d1);
        }
    } else {
        // ---- Cmat = lw@ew, lwb = lw@eb ----
        for (int idx = threadIdx.x; idx < D * ED; idx += 256) {
            const int d = idx >> 5, j = idx & 31;
            float s = 0.f;
#pragma unroll
            for (int k = 0; k < D; ++k) s = fmaf(lw[d * D + k], ew[k * ED + j], s);
            Cmat[idx] = s;
        }
        if (threadIdx.x < D) {
            float s = 0.f;
#pragma unroll
            for (int k = 0; k < D; ++k) s = fmaf(lw[threadIdx.x * D + k], eb[k], s);
            lwb[threadIdx.x] = s;
        }
    }
}

// ---------------- scan (2 kernels) ----------------

__global__ void __launch_bounds__(SCAN_BS) scan_local_k(const int* __restrict__ cnt,
                                                        int* __restrict__ base,
                                                        int* __restrict__ bsum) {
    __shared__ int s[SCAN_BS];
    const int t = threadIdx.x;
    const int i = blockIdx.x * SCAN_BS + t;
    const int v = (i < N_NODES) ? cnt[i] : 0;
    s[t] = v;
    __syncthreads();
    for (int off = 1; off < SCAN_BS; off <<= 1) {
        int tv = (t >= off) ? s[t - off] : 0;
        __syncthreads();
        s[t] += tv;
        __syncthreads();
    }
    if (i < N_NODES) base[i] = s[t] - v;
    if (t == SCAN_BS - 1) bsum[blockIdx.x] = s[t];
}

// each block reduces bsum[0..bid) itself, then adds to its slice; also fills cursor
__global__ void __launch_bounds__(SCAN_BS) scan_add_k(int* __restrict__ base,
                                                      const int* __restrict__ bsum,
                                                      int* __restrict__ cursor) {
    __shared__ int s[SCAN_BS];
    const int t = threadIdx.x;
    const int bid = blockIdx.x;
    s[t] = (t < bid) ? bsum[t] : 0;      // SCAN_NB=196 < SCAN_BS
    __syncthreads();
    for (int off = SCAN_BS / 2; off > 0; off >>= 1) {
        if (t < off) s[t] += s[t + off];
        __syncthreads();
    }
    const int boff = s[0];
    const int i = bid * SCAN_BS + t;
    if (i < N_NODES) {
        const int b = base[i] + boff;
        base[i] = b;
        cursor[i] = b;
    }
    if (bid == 0 && t == 0) base[N_NODES] = N_EDGES;
}

// ---------------- scatter: erec[pos] = {row[e], e} (8B random writes) ----------------

__global__ void __launch_bounds__(256) scatter_int2_k(const int* __restrict__ row,
                                                      const int* __restrict__ col,
                                                      int* __restrict__ cursor,
                                                      int2* __restrict__ erec) {
    int i = blockIdx.x * blockDim.x + threadIdx.x;
    int stride = gridDim.x * blockDim.x;
    for (int e = i; e < N_EDGES; e += stride) {
        const int c = col[e];
        const int r = row[e];
        const int pos = atomicAdd(&cursor[c], 1);
        erec[pos] = make_int2(r, e);
    }
}

// ---------------- merged aggregation + epilogue ----------------
// out[n][d] = inv*( segsum(xl[row]) + Cmat·segsum(ea) )[d] + [deg>0]*lwb[d] + lb[d]
// xl: 8 outstanding random 128B gathers; ea: 8 outstanding random 128B row reads
// (half-wave per edge). Both batched unconditionally, predicated adds.

__global__ void __launch_bounds__(256) agg_merged_k(const ushort* __restrict__ xl,
                                                    const float* __restrict__ ea,
                                                    const int* __restrict__ base,
                                                    const int2* __restrict__ erec,
                                                    const float* __restrict__ Cmat,
                                                    const float* __restrict__ lwb,
                                                    const float* __restrict__ lb,
                                                    float* __restrict__ out) {
    const int lane = threadIdx.x & 63;
    const int wid  = blockIdx.x * (blockDim.x >> 6) + (threadIdx.x >> 6);
    const int nw   = gridDim.x * (blockDim.x >> 6);

    const float lwbl = lwb[lane];
    const float lbl  = lb[lane];
    const float4* cm4 = (const float4*)(Cmat + (size_t)lane * ED);  // L1-hot

    const int npw = (N_NODES + nw - 1) / nw;      // contiguous node range per wave
    const int n0 = wid * npw;
    const int n1 = min(n0 + npw, N_NODES);

    for (int n = n0; n < n1; ++n) {
        const int j0 = base[n], j1 = base[n + 1];
        float ax[8] = {0,0,0,0,0,0,0,0};
        float ae[8] = {0,0,0,0,0,0,0,0};

        for (int jb = j0; jb < j1; jb += 64) {
            const int cnt = min(64, j1 - jb);               // wave-uniform
            int2 rec = erec[jb + min(lane, cnt - 1)];       // coalesced 8B

            // xl side: rounds of 8 unconditional 128B gathers
            for (int k = 0; k < cnt; k += 8) {
                float vx[8];
#pragma unroll
                for (int i = 0; i < 8; ++i) {
                    const int ri = __shfl(rec.x, min(k + i, cnt - 1));
                    vx[i] = bfu(xl[(size_t)ri * D + lane]);
                }
#pragma unroll
                for (int i = 0; i < 8; ++i) ax[i] += (k + i < cnt) ? vx[i] : 0.f;
            }

            // ea side: half-wave per edge (2 edges/instruction), rounds of 8
            const int npair = (cnt + 1) >> 1;
            const int half = lane >> 5;                     // 0 or 1
            for (int t = 0; t < npair; t += 8) {
                float ve[8];
                int pv[8];
#pragma unroll
                for (int i = 0; i < 8; ++i) {
                    const int p = min(t + i, npair - 1);
                    const int sl = min(2 * p + half, cnt - 1);
                    const int e0 = __shfl(rec.y, sl);
                    pv[i] = (t + i < npair) && (2 * p + half < cnt);
                    ve[i] = ea[(size_t)e0 * ED + (lane & 31)];
                }
#pragma unroll
                for (int i = 0; i < 8; ++i) ae[i] += pv[i] ? ve[i] : 0.f;
            }
        }

        float axs = ((ax[0]+ax[1])+(ax[2]+ax[3])) + ((ax[4]+ax[5])+(ax[6]+ax[7]));
        float aes = ((ae[0]+ae[1])+(ae[2]+ae[3])) + ((ae[4]+ae[5])+(ae[6]+ae[7]));
        aes += __shfl_xor(aes, 32);      // all lanes: segsum(ea)[n][lane&31]

        float zd = axs;
#pragma unroll
        for (int q = 0; q < ED / 4; ++q) {
            const float4 wv = cm4[q];
            zd = fmaf(__shfl(aes, 4*q+0), wv.x, zd);
            zd = fmaf(__shfl(aes, 4*q+1), wv.y, zd);
            zd = fmaf(__shfl(aes, 4*q+2), wv.z, zd);
            zd = fmaf(__shfl(aes, 4*q+3), wv.w, zd);
        }
        const int dg = j1 - j0;
        const float inv = 1.f / fmaxf((float)dg, 1.f);
        out[(size_t)n * D + lane] = fmaf(inv, zd, (dg > 0 ? lwbl : 0.f) + lbl);
    }
}

// ---------------- tier C (tiny ws): atomic version ----------------

__global__ void __launch_bounds__(256) edge_scatter_fb(
    const float* __restrict__ x, const int* __restrict__ ei,
    const float* __restrict__ ea, const float* __restrict__ ew,
    const float* __restrict__ eb, float* __restrict__ agg, float* __restrict__ deg) {
    const int lane = threadIdx.x & 63;
    const int wid  = blockIdx.x * (blockDim.x >> 6) + (threadIdx.x >> 6);
    const int nw   = gridDim.x * (blockDim.x >> 6);
    float w[ED];
#pragma unroll
    for (int k = 0; k < ED; ++k) w[k] = ew[lane * ED + k];
    const float b = eb[lane];
    for (int e = wid; e < N_EDGES; e += nw) {
        const int r = ei[e];
        const int c = ei[N_EDGES + e];
        const float4* ea4 = (const float4*)(ea + (size_t)e * ED);
        float acc = b;
#pragma unroll
        for (int q = 0; q < ED / 4; ++q) {
            float4 v = ea4[q];
            acc = fmaf(v.x, w[4*q+0], acc); acc = fmaf(v.y, w[4*q+1], acc);
            acc = fmaf(v.z, w[4*q+2], acc); acc = fmaf(v.w, w[4*q+3], acc);
        }
        acc += x[(size_t)r * D + lane];
        atomicAdd(&agg[(size_t)c * D + lane], acc);
        if (lane == 0) atomicAdd(&deg[c], 1.0f);
    }
}

__global__ void __launch_bounds__(256) node_linear_fb(
    float* __restrict__ agg, const float* __restrict__ deg,
    const float* __restrict__ lw, const float* __restrict__ lb) {
    const int lane = threadIdx.x & 63;
    const int wid  = blockIdx.x * (blockDim.x >> 6) + (threadIdx.x >> 6);
    const int nw   = gridDim.x * (blockDim.x >> 6);
    float w[D];
#pragma unroll
    for (int k = 0; k < D; ++k) w[k] = lw[lane * D + k];
    const float b = lb[lane];
    for (int n = wid; n < N_NODES; n += nw) {
        const float inv = 1.0f / fmaxf(deg[n], 1.0f);
        const float4* a4 = (const float4*)(agg + (size_t)n * D);
        float dot = 0.0f;
#pragma unroll
        for (int q = 0; q < D / 4; ++q) {
            float4 v = a4[q];
            dot = fmaf(v.x, w[4*q+0], dot); dot = fmaf(v.y, w[4*q+1], dot);
            dot = fmaf(v.z, w[4*q+2], dot); dot = fmaf(v.w, w[4*q+3], dot);
        }
        agg[(size_t)n * D + lane] = fmaf(inv, dot, b);
    }
}

// ---------------- launch ----------------

extern "C" void kernel_launch(void* const* d_in, const int* in_sizes, int n_in,
                              void* d_out, int out_size, void* d_ws, size_t ws_size,
                              hipStream_t stream) {
    const float* x  = (const float*)d_in[0];
    const int*   ei = (const int*)d_in[1];     // [2][E]: rows then cols
    const float* ea = (const float*)d_in[2];
    const float* lw = (const float*)d_in[3];
    const float* lb = (const float*)d_in[4];
    const float* ew = (const float*)d_in[5];
    const float* eb = (const float*)d_in[6];
    const int* row = ei;
    const int* col = ei + N_EDGES;

    char* ws = (char*)d_ws;
    float* zout = (float*)d_out;

    // ws layout (bytes)
    const size_t W_EREC = 0;                   // E int2   = 10,000,000
    const size_t W_XL   = 10000000;            // N*64 ushort = 12,800,000
    const size_t W_CNT  = 22800000;            // N ints (doubles as cursor)
    const size_t W_BASE = 23200000;            // N+1 ints (+pad)
    const size_t W_BSUM = 23600016;            // 196 ints
    const size_t W_CMAT = 23600800;            // 2048 floats
    const size_t W_LWB  = 23608992;            // 64 floats
    const size_t REQ    = 23609248;

    if (ws_size >= REQ) {
        int2*   erec = (int2*)(ws + W_EREC);
        ushort* xl   = (ushort*)(ws + W_XL);
        int*    cnt  = (int*)(ws + W_CNT);
        int*    base = (int*)(ws + W_BASE);
        int*    bsum = (int*)(ws + W_BSUM);
        float*  Cmat = (float*)(ws + W_CMAT);
        float*  lwbv = (float*)(ws + W_LWB);

        hipMemsetAsync(cnt, 0, (size_t)N_NODES * sizeof(int), stream);
        prep_k       <<<2049, 256, 0, stream>>>(col, cnt, x, lw, xl, ew, eb, Cmat, lwbv);
        scan_local_k <<<SCAN_NB, SCAN_BS, 0, stream>>>(cnt, base, bsum);
        scan_add_k   <<<SCAN_NB, SCAN_BS, 0, stream>>>(base, bsum, cnt /*cursor*/);
        scatter_int2_k<<<2048, 256, 0, stream>>>(row, col, cnt /*cursor*/, erec);
        agg_merged_k <<<2048, 256, 0, stream>>>(xl, ea, base, erec, Cmat, lwbv, lb, zout);
    } else {
        float* deg = (float*)d_ws;
        hipMemsetAsync(zout, 0, (size_t)N_NODES * D * sizeof(float), stream);
        hipMemsetAsync(deg, 0, (size_t)N_NODES * sizeof(float), stream);
        edge_scatter_fb<<<2048, 256, 0, stream>>>(x, ei, ea, ew, eb, zout, deg);
        node_linear_fb <<<1024, 256, 0, stream>>>(zout, deg, lw, lb);
    }
}

// Round 8
// 285.921 us; speedup vs baseline: 1.2865x; 1.1903x over previous
//
#include <hip/hip_runtime.h>

#define N_NODES 100000
#define N_EDGES 1250000
#define D 64
#define ED 32
#define CAP 40      // bucket capacity; Poisson(12.5) max-deg@100k ~ 30

typedef unsigned int uint;
typedef unsigned short ushort;

__device__ __forceinline__ uint bfr(float f) {
    uint u = __float_as_uint(f);
    return (u + 0x7FFFu + ((u >> 16) & 1u)) >> 16;
}
__device__ __forceinline__ float bfu(ushort s) { return __uint_as_float(((uint)s) << 16); }

// ---------------- bucket scatter: erec[c*CAP+pos] = {row, e}; overflow to list ----------------

__global__ void __launch_bounds__(256) scatter_bucket_k(const int* __restrict__ row,
                                                        const int* __restrict__ col,
                                                        int* __restrict__ cursor,   // zeroed; becomes deg
                                                        int2* __restrict__ erec,
                                                        int4* __restrict__ ovf,
                                                        int* __restrict__ ovfcnt) {
    int i = blockIdx.x * blockDim.x + threadIdx.x;
    const int stride = gridDim.x * blockDim.x;
    for (int e = i; e < N_EDGES; e += stride) {
        const int c = col[e];
        const int r = row[e];
        const int pos = atomicAdd(&cursor[c], 1);
        if (pos < CAP) {
            erec[(size_t)c * CAP + pos] = make_int2(r, e);
        } else {
            const int o = atomicAdd(ovfcnt, 1);
            ovf[o] = make_int4(c, r, e, 0);
        }
    }
}

// ---------------- xl16 = bf16(x @ lw^T) (blocks 0..1023) | Cmat,lwb (block 1024) ----------------

__global__ void __launch_bounds__(256) xl16_combine_k(const float* __restrict__ x,
                                                      const float* __restrict__ lw,
                                                      ushort* __restrict__ xl,
                                                      const float* __restrict__ ew,
                                                      const float* __restrict__ eb,
                                                      float* __restrict__ Cmat,
                                                      float* __restrict__ lwb) {
    const int bid = blockIdx.x;
    if (bid < 1024) {
        const int lane = threadIdx.x & 63;
        const int wid  = bid * 4 + (threadIdx.x >> 6);
        const int nw   = 1024 * 4;

        float w[D];
        const float4* lw4 = (const float4*)(lw + (size_t)lane * D);
#pragma unroll
        for (int q = 0; q < D / 4; ++q) {
            const float4 v = lw4[q];
            w[4*q+0] = v.x; w[4*q+1] = v.y; w[4*q+2] = v.z; w[4*q+3] = v.w;
        }
        for (int n = wid; n < N_NODES; n += nw) {
            const float4* xx = (const float4*)(x + (size_t)n * D);
            float d0 = 0.f, d1 = 0.f;
#pragma unroll
            for (int q = 0; q < D / 8; ++q) {
                const float4 v0 = xx[q];
                const float4 v1 = xx[q + 8];
                d0 = fmaf(v0.x, w[4*q+0], d0);  d0 = fmaf(v0.y, w[4*q+1], d0);
                d0 = fmaf(v0.z, w[4*q+2], d0);  d0 = fmaf(v0.w, w[4*q+3], d0);
                d1 = fmaf(v1.x, w[4*q+32], d1); d1 = fmaf(v1.y, w[4*q+33], d1);
                d1 = fmaf(v1.z, w[4*q+34], d1); d1 = fmaf(v1.w, w[4*q+35], d1);
            }
            xl[(size_t)n * D + lane] = (ushort)bfr(d0 + d1);
        }
    } else {
        for (int idx = threadIdx.x; idx < D * ED; idx += 256) {
            const int d = idx >> 5, j = idx & 31;
            float s = 0.f;
#pragma unroll
            for (int k = 0; k < D; ++k) s = fmaf(lw[d * D + k], ew[k * ED + j], s);
            Cmat[idx] = s;
        }
        if (threadIdx.x < D) {
            float s = 0.f;
#pragma unroll
            for (int k = 0; k < D; ++k) s = fmaf(lw[threadIdx.x * D + k], eb[k], s);
            lwb[threadIdx.x] = s;
        }
    }
}

// ---------------- aggregation + epilogue (bucketed, single block-iteration) ----------------
// out[n][d] = inv*( segsum(xl[row]) + Cmat·segsum(ea) )[d] + [deg>0]*lwb[d] + lb[d]

__global__ void __launch_bounds__(256) agg_bucket_k(const ushort* __restrict__ xl,
                                                    const float* __restrict__ ea,
                                                    const int* __restrict__ deg_,   // = cursor
                                                    const int2* __restrict__ erec,
                                                    const int4* __restrict__ ovf,
                                                    const int* __restrict__ ovfcnt,
                                                    const float* __restrict__ Cmat,
                                                    const float* __restrict__ lwb,
                                                    const float* __restrict__ lb,
                                                    float* __restrict__ out) {
    const int lane = threadIdx.x & 63;
    const int wid  = blockIdx.x * (blockDim.x >> 6) + (threadIdx.x >> 6);
    const int nw   = gridDim.x * (blockDim.x >> 6);

    const float lwbl = lwb[lane];
    const float lbl  = lb[lane];
    const float4* cm4 = (const float4*)(Cmat + (size_t)lane * ED);  // L1-hot
    const int novf = *ovfcnt;                                       // almost always 0

    for (int n = wid; n < N_NODES; n += nw) {
        const int deg  = deg_[n];
        const int degb = min(deg, CAP);
        float ax[8] = {0,0,0,0,0,0,0,0};
        float ae[8] = {0,0,0,0,0,0,0,0};

        if (degb > 0) {
            const int2 rec = erec[(size_t)n * CAP + min(lane, degb - 1)];  // coalesced

            // ---- xl gathers: unpredicated full rounds + one predicated tail ----
            const int full = degb & ~7;
            for (int k = 0; k < full; k += 8) {
                float vx[8];
#pragma unroll
                for (int i = 0; i < 8; ++i)
                    vx[i] = bfu(xl[(size_t)__shfl(rec.x, k + i) * D + lane]);
#pragma unroll
                for (int i = 0; i < 8; ++i) ax[i] += vx[i];
            }
            if (full < degb) {
                float vx[8];
#pragma unroll
                for (int i = 0; i < 8; ++i)
                    vx[i] = bfu(xl[(size_t)__shfl(rec.x, min(full + i, degb - 1)) * D + lane]);
#pragma unroll
                for (int i = 0; i < 8; ++i) ax[i] += (full + i < degb) ? vx[i] : 0.f;
            }

            // ---- ea reads: half-wave per edge (2 edges/instr), rounds of 8 ----
            const int npair = (degb + 1) >> 1;          // <= 20
            const int half = lane >> 5;
            for (int t = 0; t < npair; t += 8) {
                float ve[8];
                int pv[8];
#pragma unroll
                for (int i = 0; i < 8; ++i) {
                    const int p  = min(t + i, npair - 1);
                    const int sl = min(2 * p + half, degb - 1);
                    const int e0 = __shfl(rec.y, sl);
                    pv[i] = (t + i < npair) && (2 * p + half < degb);
                    ve[i] = ea[(size_t)e0 * ED + (lane & 31)];
                }
#pragma unroll
                for (int i = 0; i < 8; ++i) ae[i] += pv[i] ? ve[i] : 0.f;
            }
        }

        // ---- overflow edges (correctness path; novf==0 in practice) ----
        if (novf > 0) {
            for (int o = 0; o < novf; ++o) {
                const int4 v = ovf[o];
                if (v.x == n) {
                    ax[0] += bfu(xl[(size_t)v.y * D + lane]);
                    if (lane < ED) ae[0] += ea[(size_t)v.z * ED + lane];
                }
            }
        }

        float axs = ((ax[0]+ax[1])+(ax[2]+ax[3])) + ((ax[4]+ax[5])+(ax[6]+ax[7]));
        float aes = ((ae[0]+ae[1])+(ae[2]+ae[3])) + ((ae[4]+ae[5])+(ae[6]+ae[7]));
        aes += __shfl_xor(aes, 32);          // all lanes hold segsum(ea)[n][lane&31]

        float zd = axs;
#pragma unroll
        for (int q = 0; q < ED / 4; ++q) {
            const float4 wv = cm4[q];
            zd = fmaf(__shfl(aes, 4*q+0), wv.x, zd);
            zd = fmaf(__shfl(aes, 4*q+1), wv.y, zd);
            zd = fmaf(__shfl(aes, 4*q+2), wv.z, zd);
            zd = fmaf(__shfl(aes, 4*q+3), wv.w, zd);
        }
        const float inv = 1.f / fmaxf((float)deg, 1.f);
        out[(size_t)n * D + lane] = fmaf(inv, zd, (deg > 0 ? lwbl : 0.f) + lbl);
    }
}

// ---------------- tier C (tiny ws): atomic version ----------------

__global__ void __launch_bounds__(256) edge_scatter_fb(
    const float* __restrict__ x, const int* __restrict__ ei,
    const float* __restrict__ ea, const float* __restrict__ ew,
    const float* __restrict__ eb, float* __restrict__ agg, float* __restrict__ deg) {
    const int lane = threadIdx.x & 63;
    const int wid  = blockIdx.x * (blockDim.x >> 6) + (threadIdx.x >> 6);
    const int nw   = gridDim.x * (blockDim.x >> 6);
    float w[ED];
#pragma unroll
    for (int k = 0; k < ED; ++k) w[k] = ew[lane * ED + k];
    const float b = eb[lane];
    for (int e = wid; e < N_EDGES; e += nw) {
        const int r = ei[e];
        const int c = ei[N_EDGES + e];
        const float4* ea4 = (const float4*)(ea + (size_t)e * ED);
        float acc = b;
#pragma unroll
        for (int q = 0; q < ED / 4; ++q) {
            float4 v = ea4[q];
            acc = fmaf(v.x, w[4*q+0], acc); acc = fmaf(v.y, w[4*q+1], acc);
            acc = fmaf(v.z, w[4*q+2], acc); acc = fmaf(v.w, w[4*q+3], acc);
        }
        acc += x[(size_t)r * D + lane];
        atomicAdd(&agg[(size_t)c * D + lane], acc);
        if (lane == 0) atomicAdd(&deg[c], 1.0f);
    }
}

__global__ void __launch_bounds__(256) node_linear_fb(
    float* __restrict__ agg, const float* __restrict__ deg,
    const float* __restrict__ lw, const float* __restrict__ lb) {
    const int lane = threadIdx.x & 63;
    const int wid  = blockIdx.x * (blockDim.x >> 6) + (threadIdx.x >> 6);
    const int nw   = gridDim.x * (blockDim.x >> 6);
    float w[D];
#pragma unroll
    for (int k = 0; k < D; ++k) w[k] = lw[lane * D + k];
    const float b = lb[lane];
    for (int n = wid; n < N_NODES; n += nw) {
        const float inv = 1.0f / fmaxf(deg[n], 1.0f);
        const float4* a4 = (const float4*)(agg + (size_t)n * D);
        float dot = 0.0f;
#pragma unroll
        for (int q = 0; q < D / 4; ++q) {
            float4 v = a4[q];
            dot = fmaf(v.x, w[4*q+0], dot); dot = fmaf(v.y, w[4*q+1], dot);
            dot = fmaf(v.z, w[4*q+2], dot); dot = fmaf(v.w, w[4*q+3], dot);
        }
        agg[(size_t)n * D + lane] = fmaf(inv, dot, b);
    }
}

// ---------------- launch ----------------

extern "C" void kernel_launch(void* const* d_in, const int* in_sizes, int n_in,
                              void* d_out, int out_size, void* d_ws, size_t ws_size,
                              hipStream_t stream) {
    const float* x  = (const float*)d_in[0];
    const int*   ei = (const int*)d_in[1];     // [2][E]: rows then cols
    const float* ea = (const float*)d_in[2];
    const float* lw = (const float*)d_in[3];
    const float* lb = (const float*)d_in[4];
    const float* ew = (const float*)d_in[5];
    const float* eb = (const float*)d_in[6];
    const int* row = ei;
    const int* col = ei + N_EDGES;

    char* ws = (char*)d_ws;
    float* zout = (float*)d_out;

    // ws layout (bytes)
    const size_t W_EREC = 0;                           // N*CAP int2 = 32,000,000
    const size_t W_OVF  = (size_t)N_NODES * CAP * 8;   // E int4     = 20,000,000
    const size_t W_XL   = W_OVF + (size_t)N_EDGES * 16;        // 12,800,000
    const size_t W_CNT  = W_XL + (size_t)N_NODES * D * 2;      //    400,000
    const size_t W_OVFC = W_CNT + (size_t)N_NODES * 4;         //          4 (+pad)
    const size_t W_CMAT = W_OVFC + 16;                         //      8,192
    const size_t W_LWB  = W_CMAT + D * ED * 4;                 //        256
    const size_t REQ    = W_LWB + D * 4;

    if (ws_size >= REQ) {
        int2*   erec = (int2*)(ws + W_EREC);
        int4*   ovf  = (int4*)(ws + W_OVF);
        ushort* xl   = (ushort*)(ws + W_XL);
        int*    cnt  = (int*)(ws + W_CNT);
        int*    ovfc = (int*)(ws + W_OVFC);
        float*  Cmat = (float*)(ws + W_CMAT);
        float*  lwbv = (float*)(ws + W_LWB);

        // cursor + ovfcnt in one memset (adjacent)
        hipMemsetAsync(cnt, 0, (size_t)N_NODES * sizeof(int) + 16, stream);
        scatter_bucket_k<<<2048, 256, 0, stream>>>(row, col, cnt, erec, ovf, ovfc);
        xl16_combine_k  <<<1025, 256, 0, stream>>>(x, lw, xl, ew, eb, Cmat, lwbv);
        agg_bucket_k    <<<4096, 256, 0, stream>>>(xl, ea, cnt, erec, ovf, ovfc,
                                                   Cmat, lwbv, lb, zout);
    } else {
        float* deg = (float*)d_ws;
        hipMemsetAsync(zout, 0, (size_t)N_NODES * D * sizeof(float), stream);
        hipMemsetAsync(deg, 0, (size_t)N_NODES * sizeof(float), stream);
        edge_scatter_fb<<<2048, 256, 0, stream>>>(x, ei, ea, ew, eb, zout, deg);
        node_linear_fb <<<1024, 256, 0, stream>>>(zout, deg, lw, lb);
    }
}